// Round 6
// baseline (184.504 us; speedup 1.0000x reference)
//
#include <hip/hip_runtime.h>
#include <stdint.h>

#define N_DIM 4096
#define B_DIM 64
#define OUTSZ (B_DIM * N_DIM)        // 262144 elements per output plane

typedef __bf16 bf16x8 __attribute__((ext_vector_type(8)));
typedef float floatx4 __attribute__((ext_vector_type(4)));

union FragU { uint4 u; bf16x8 h; };

__device__ __forceinline__ unsigned short f2bf_rne(float f) {
    unsigned int u = __float_as_uint(f);
    u += 0x7fffu + ((u >> 16) & 1u);
    return (unsigned short)(u >> 16);
}

// c = Vmag*cos(ang), s = Vmag*sin(ang).
// fp32 copies in natural [b][j] layout (epilogue), bf16 copies packed in MFMA
// B-fragment order: idx = ((j>>3)*64 + b)*8 + (j&7)
__global__ __launch_bounds__(256) void pf_prep(
        const float* __restrict__ Vmag, const float* __restrict__ Vang,
        unsigned short* __restrict__ c_pk, unsigned short* __restrict__ s_pk,
        float* __restrict__ c_f, float* __restrict__ s_f) {
    int idx = blockIdx.x * 256 + threadIdx.x;   // = b*4096 + j
    int b = idx >> 12;
    int j = idx & 4095;
    float sv, cv;
    sincosf(Vang[idx], &sv, &cv);
    float v = Vmag[idx];
    float c = v * cv;
    float s = v * sv;
    c_f[idx] = c;
    s_f[idx] = s;
    int p = (((j >> 3) << 6) + b) * 8 + (j & 7);
    c_pk[p] = f2bf_rne(c);
    s_pk[p] = f2bf_rne(s);
}

// Linear-stream GEMM. Grid 256 blocks; block b owns out-rows {b + 256*s}.
// Sweep s: all 1024 threads read row (b+256s) contiguously (16KB) -> chip-wide
// the 256 blocks sweep G (then B) front-to-back in contiguous 4MB epochs =
// pure streaming pattern. Rows staged to LDS as bf16 (16 rows x 4096 = 128KB).
// Pass 1 (G): acc1 += G*c, acc2 += G*s. Pass 2 (B, LDS reused):
// acc1 += B*s, acc2 += B*(-c). => acc1 = X, acc2 = Y.
// K split across 16 waves (256 each, 8 MFMA-steps); cs frags direct from L2.
#define ROWH 4104                     // LDS row stride in halves (8208B, 16B-aligned)
__global__ __launch_bounds__(1024, 4) void pf_gemm(
        const float* __restrict__ G, const float* __restrict__ Bm,
        const unsigned short* __restrict__ c_pk, const unsigned short* __restrict__ s_pk,
        float* __restrict__ wsX, float* __restrict__ wsY) {
    __shared__ __align__(16) unsigned short lds_a[16 * ROWH];   // 131328 B
    const int tid = threadIdx.x;
    const int wave = tid >> 6;        // 0..15
    const int lane = tid & 63;
    const int n = lane & 15;          // A-row (LDS row) / C col
    const int quad = lane >> 4;       // k-subgroup of 8 / C row-group of 4
    const int b = blockIdx.x;         // block's base row; rows = b + 256*s

    floatx4 acc1[4], acc2[4];
    #pragma unroll
    for (int t = 0; t < 4; ++t) {
        acc1[t] = (floatx4){0.f, 0.f, 0.f, 0.f};
        acc2[t] = (floatx4){0.f, 0.f, 0.f, 0.f};
    }

    const int kw = wave << 8;         // wave's K-chunk base (256)

    #pragma unroll 1
    for (int pass = 0; pass < 2; ++pass) {
        const float* M = (pass == 0) ? G : Bm;
        // ---- stage 16 rows (linear chip-wide sweeps), fp32 -> bf16 ----
        const float* base = M + (size_t)b * N_DIM + (tid << 2);
        #pragma unroll 4
        for (int s = 0; s < 16; ++s) {
            float4 v = *(const float4*)(base + ((size_t)s << 20));  // +s*256 rows
            unsigned short w0 = f2bf_rne(v.x), w1 = f2bf_rne(v.y);
            unsigned short w2 = f2bf_rne(v.z), w3 = f2bf_rne(v.w);
            ushort4 pk = {w0, w1, w2, w3};
            *(ushort4*)&lds_a[s * ROWH + (tid << 2)] = pk;          // 8B store
        }
        __syncthreads();   // rows staged (and, pass 1: all pass-0 reads done)

        // ---- compute: 8 steps of K=32 ----
        #pragma unroll 1
        for (int st = 0; st < 8; ++st) {
            const int k0 = kw + (st << 5);
            bf16x8 am = *(const bf16x8*)&lds_a[(size_t)n * ROWH + k0 + (quad << 3)];
            const int kg = (k0 >> 3) + quad;   // k-group
            const unsigned short* cpp = c_pk + ((size_t)kg << 9) + (n << 3);
            const unsigned short* spp = s_pk + ((size_t)kg << 9) + (n << 3);
            uint4 cu[4], su[4];
            #pragma unroll
            for (int t = 0; t < 4; ++t) cu[t] = *(const uint4*)(cpp + (t << 7));
            #pragma unroll
            for (int t = 0; t < 4; ++t) su[t] = *(const uint4*)(spp + (t << 7));

            if (pass == 0) {
                // acc1 += G*c ; acc2 += G*s
                #pragma unroll
                for (int t = 0; t < 4; ++t) {
                    FragU cf, sf;
                    cf.u = cu[t]; sf.u = su[t];
                    acc1[t] = __builtin_amdgcn_mfma_f32_16x16x32_bf16(am, cf.h, acc1[t], 0, 0, 0);
                    acc2[t] = __builtin_amdgcn_mfma_f32_16x16x32_bf16(am, sf.h, acc2[t], 0, 0, 0);
                }
            } else {
                // acc1 += B*s ; acc2 += B*(-c)
                #pragma unroll
                for (int t = 0; t < 4; ++t) {
                    FragU sf, nf;
                    sf.u = su[t];
                    nf.u.x = cu[t].x ^ 0x80008000u;
                    nf.u.y = cu[t].y ^ 0x80008000u;
                    nf.u.z = cu[t].z ^ 0x80008000u;
                    nf.u.w = cu[t].w ^ 0x80008000u;
                    acc1[t] = __builtin_amdgcn_mfma_f32_16x16x32_bf16(am, sf.h, acc1[t], 0, 0, 0);
                    acc2[t] = __builtin_amdgcn_mfma_f32_16x16x32_bf16(am, nf.h, acc2[t], 0, 0, 0);
                }
            }
        }
        __syncthreads();   // all LDS reads done before restage / reduction reuse
    }

    // ---- cross-wave reduction (16 -> 8 -> sum), LDS aliased over staging ----
    // C/D layout: col(bcol) = lane&15 (+16t), row(m) = quad*4 + r
    float* red = (float*)lds_a;       // [2][8][16][66] = 67584 B <= 131328
    #define RD(x, w_, m, bb) red[((((x) * 8 + (w_)) * 16 + (m)) * 66) + (bb)]
    if (wave >= 8) {
        #pragma unroll
        for (int t = 0; t < 4; ++t)
            #pragma unroll
            for (int r = 0; r < 4; ++r) {
                RD(0, wave - 8, (quad << 2) + r, (t << 4) + n) = acc1[t][r];
                RD(1, wave - 8, (quad << 2) + r, (t << 4) + n) = acc2[t][r];
            }
    }
    __syncthreads();
    if (wave < 8) {
        #pragma unroll
        for (int t = 0; t < 4; ++t)
            #pragma unroll
            for (int r = 0; r < 4; ++r) {
                RD(0, wave, (quad << 2) + r, (t << 4) + n) += acc1[t][r];
                RD(1, wave, (quad << 2) + r, (t << 4) + n) += acc2[t][r];
            }
    }
    __syncthreads();

    // ---- final sum + scatter-write X,Y planes (cache-resident ws) ----
    {
        const int bb = tid >> 4;      // bcol 0..63
        const int m = tid & 15;       // out-row index s
        float X = 0.f, Y = 0.f;
        #pragma unroll
        for (int w = 0; w < 8; ++w) {
            X += RD(0, w, m, bb);
            Y += RD(1, w, m, bb);
        }
        size_t off = (size_t)bb * N_DIM + b + (m << 8);   // i = b + 256*m
        wsX[off] = X;
        wsY[off] = Y;
    }
}

// Linear elementwise epilogue over the X,Y planes.
__global__ __launch_bounds__(256) void pf_reduce(
        const float* __restrict__ wsX, const float* __restrict__ wsY,
        const float* __restrict__ c_f, const float* __restrict__ s_f,
        const float* __restrict__ P_in, const float* __restrict__ Q_in,
        float* __restrict__ out) {
    int e = (blockIdx.x * 256 + threadIdx.x) * 4;
    float4 X = *(const float4*)(wsX + e);
    float4 Y = *(const float4*)(wsY + e);
    float4 c = *(const float4*)(c_f + e);
    float4 s = *(const float4*)(s_f + e);
    float4 P = *(const float4*)(P_in + e);
    float4 Q = *(const float4*)(Q_in + e);
    float4 rp, rq;
    rp.x = c.x * X.x + s.x * Y.x - P.x;  rq.x = s.x * X.x - c.x * Y.x - Q.x;
    rp.y = c.y * X.y + s.y * Y.y - P.y;  rq.y = s.y * X.y - c.y * Y.y - Q.y;
    rp.z = c.z * X.z + s.z * Y.z - P.z;  rq.z = s.z * X.z - c.z * Y.z - Q.z;
    rp.w = c.w * X.w + s.w * Y.w - P.w;  rq.w = s.w * X.w - c.w * Y.w - Q.w;
    *(float4*)(out + e) = rp;
    *(float4*)(out + OUTSZ + e) = rq;
}

extern "C" void kernel_launch(void* const* d_in, const int* in_sizes, int n_in,
                              void* d_out, int out_size, void* d_ws, size_t ws_size,
                              hipStream_t stream) {
    const float* Vmag = (const float*)d_in[0];
    const float* Vang = (const float*)d_in[1];
    const float* P_in = (const float*)d_in[2];
    const float* Q_in = (const float*)d_in[3];
    const float* G    = (const float*)d_in[4];
    const float* Bm   = (const float*)d_in[5];
    float* out = (float*)d_out;

    char* ws = (char*)d_ws;
    unsigned short* c_pk = (unsigned short*)(ws);                    // 512 KB
    unsigned short* s_pk = (unsigned short*)(ws + (512u << 10));     // 512 KB
    float* c_f = (float*)(ws + (1u << 20));                          // 1 MB
    float* s_f = (float*)(ws + (2u << 20));                          // 1 MB
    float* wsX = (float*)(ws + (3u << 20));                          // 1 MB
    float* wsY = (float*)(ws + (4u << 20));                          // 1 MB

    hipLaunchKernelGGL(pf_prep, dim3((B_DIM * N_DIM) / 256), dim3(256), 0, stream,
                       Vmag, Vang, c_pk, s_pk, c_f, s_f);
    hipLaunchKernelGGL(pf_gemm, dim3(256), dim3(1024), 0, stream,
                       G, Bm, c_pk, s_pk, wsX, wsY);
    hipLaunchKernelGGL(pf_reduce, dim3(OUTSZ / 1024), dim3(256), 0, stream,
                       wsX, wsY, c_f, s_f, P_in, Q_in, out);
}

// Round 7
// 174.639 us; speedup vs baseline: 1.0565x; 1.0565x over previous
//
#include <hip/hip_runtime.h>
#include <stdint.h>

#define N_DIM 4096
#define B_DIM 64
#define OUTSZ (B_DIM * N_DIM)        // 262144 elements per output plane

typedef __bf16 bf16x8 __attribute__((ext_vector_type(8)));
typedef float floatx4 __attribute__((ext_vector_type(4)));

union FragU { uint4 u; bf16x8 h; };

__device__ __forceinline__ unsigned short f2bf_rne(float f) {
    unsigned int u = __float_as_uint(f);
    u += 0x7fffu + ((u >> 16) & 1u);
    return (unsigned short)(u >> 16);
}

// c = Vmag*cos(ang), s = Vmag*sin(ang).
// fp32 copies in natural [b][j] layout (epilogue), bf16 copies packed in MFMA
// B-fragment order: idx = ((j>>3)*64 + b)*8 + (j&7)
__global__ __launch_bounds__(256) void pf_prep(
        const float* __restrict__ Vmag, const float* __restrict__ Vang,
        unsigned short* __restrict__ c_pk, unsigned short* __restrict__ s_pk,
        float* __restrict__ c_f, float* __restrict__ s_f) {
    int idx = blockIdx.x * 256 + threadIdx.x;   // = b*4096 + j
    int b = idx >> 12;
    int j = idx & 4095;
    float sv, cv;
    sincosf(Vang[idx], &sv, &cv);
    float v = Vmag[idx];
    float c = v * cv;
    float s = v * sv;
    c_f[idx] = c;
    s_f[idx] = s;
    int p = (((j >> 3) << 6) + b) * 8 + (j & 7);
    c_pk[p] = f2bf_rne(c);
    s_pk[p] = f2bf_rne(s);
}

// Byte-minimized GEMM. Grid 256 = 32 rowgroups(128 rows) x 8 K-chunks(512).
// Per-block vmem bytes: A (G/B fp32, read-once) 512 KB + cs slice 128 KB
// (staged to LDS ONCE, one barrier, shared by all waves) + partials 64 KB
// => chip total ~196 MB vs R1's 384 MB. K-loop is barrier-free (R1 structure):
// A direct loads prefetched 1 deep (vmcnt); cs frags via ds_read (lgkmcnt,
// never drains the A prefetch). 16 waves = 8 row-stripes x 2 K-subchunks.
// X = G*c + B*s ; Y = G*s - B*c (-c via sign-bit XOR).
__global__ __launch_bounds__(1024, 4) void pf_gemm(
        const float* __restrict__ G, const float* __restrict__ Bm,
        const unsigned short* __restrict__ c_pk, const unsigned short* __restrict__ s_pk,
        float* __restrict__ ws_part) {
    __shared__ __align__(16) unsigned short lds_cs[65536];   // c:0..32K s:32K..64K (128KB)
    const int tid = threadIdx.x;
    const int wave = tid >> 6;        // 0..15
    const int lane = tid & 63;
    const int n = lane & 15;          // A row / C col
    const int quad = lane >> 4;       // k-subgroup of 8 / C row-group of 4
    const int rg = blockIdx.x >> 3;   // row group (128 rows)
    const int kc = blockIdx.x & 7;    // K-chunk (512)
    const int stripe = wave & 7;      // 16-row stripe
    const int t2 = wave >> 3;         // K-subchunk (256)

    // ---- stage cs slice (128 KB) into LDS, coalesced, once ----
    {
        const unsigned short* csrc = c_pk + ((size_t)kc << 15);
        const unsigned short* ssrc = s_pk + ((size_t)kc << 15);
        #pragma unroll
        for (int j = 0; j < 4; ++j) {
            const int o = (j << 13) + (tid << 3);
            *(uint4*)&lds_cs[o]         = *(const uint4*)(csrc + o);
            *(uint4*)&lds_cs[32768 + o] = *(const uint4*)(ssrc + o);
        }
    }

    const int row = (rg << 7) + (stripe << 4) + n;
    const int kb = (kc << 9) + (t2 << 8);
    const float* gp = G  + (size_t)row * N_DIM + kb + (quad << 3);
    const float* bp = Bm + (size_t)row * N_DIM + kb + (quad << 3);

    floatx4 accX[4], accY[4];
    #pragma unroll
    for (int t = 0; t < 4; ++t) {
        accX[t] = (floatx4){0.f, 0.f, 0.f, 0.f};
        accY[t] = (floatx4){0.f, 0.f, 0.f, 0.f};
    }

    // preload iter 0's A operands (overlaps the staging barrier)
    float4 g0 = *(const float4*)gp;
    float4 g1 = *(const float4*)(gp + 4);
    float4 h0 = *(const float4*)bp;
    float4 h1 = *(const float4*)(bp + 4);
    gp += 32; bp += 32;

    __syncthreads();                  // cs slice visible to all waves

    #pragma unroll 1
    for (int it = 0; it < 8; ++it) {
        float4 ng0, ng1, nh0, nh1;
        if (it < 7) {                 // prefetch next iter's A (vmcnt; nothing
            ng0 = *(const float4*)gp;            //  below waits on vmcnt)
            ng1 = *(const float4*)(gp + 4);
            nh0 = *(const float4*)bp;
            nh1 = *(const float4*)(bp + 4);
            gp += 32; bp += 32;
        }

        // cs fragments from LDS: local k-group = t2*32 + it*4 + quad
        const int kg = (t2 << 5) + (it << 2) + quad;
        const int fo = (kg << 9) + (n << 3);
        uint4 cu[4], su[4];
        #pragma unroll
        for (int t = 0; t < 4; ++t) cu[t] = *(const uint4*)&lds_cs[fo + (t << 7)];
        #pragma unroll
        for (int t = 0; t < 4; ++t) su[t] = *(const uint4*)&lds_cs[32768 + fo + (t << 7)];

        bf16x8 ag, ah;
        ag[0] = (__bf16)g0.x; ag[1] = (__bf16)g0.y; ag[2] = (__bf16)g0.z; ag[3] = (__bf16)g0.w;
        ag[4] = (__bf16)g1.x; ag[5] = (__bf16)g1.y; ag[6] = (__bf16)g1.z; ag[7] = (__bf16)g1.w;
        ah[0] = (__bf16)h0.x; ah[1] = (__bf16)h0.y; ah[2] = (__bf16)h0.z; ah[3] = (__bf16)h0.w;
        ah[4] = (__bf16)h1.x; ah[5] = (__bf16)h1.y; ah[6] = (__bf16)h1.z; ah[7] = (__bf16)h1.w;

        // c-phase: X += G*c ; Y += B*(-c)
        #pragma unroll
        for (int t = 0; t < 4; ++t) {
            FragU cf, nf;
            cf.u = cu[t];
            nf.u.x = cu[t].x ^ 0x80008000u;
            nf.u.y = cu[t].y ^ 0x80008000u;
            nf.u.z = cu[t].z ^ 0x80008000u;
            nf.u.w = cu[t].w ^ 0x80008000u;
            accX[t] = __builtin_amdgcn_mfma_f32_16x16x32_bf16(ag, cf.h, accX[t], 0, 0, 0);
            accY[t] = __builtin_amdgcn_mfma_f32_16x16x32_bf16(ah, nf.h, accY[t], 0, 0, 0);
        }
        // s-phase: X += B*s ; Y += G*s
        #pragma unroll
        for (int t = 0; t < 4; ++t) {
            FragU sf;
            sf.u = su[t];
            accX[t] = __builtin_amdgcn_mfma_f32_16x16x32_bf16(ah, sf.h, accX[t], 0, 0, 0);
            accY[t] = __builtin_amdgcn_mfma_f32_16x16x32_bf16(ag, sf.h, accY[t], 0, 0, 0);
        }

        if (it < 7) { g0 = ng0; g1 = ng1; h0 = nh0; h1 = nh1; }
    }

    // ---- reduce across the 2 K-subchunks; red aliased over cs LDS ----
    // C/D layout: col(b) = lane&15 (+16t), row(m) = quad*4 + r
    float* red = (float*)lds_cs;      // [2][8][16][66] = 67584 B <= 131072
    #define RD(x, s_, m, bb) red[((((x) * 8 + (s_)) * 16 + (m)) * 66) + (bb)]
    __syncthreads();                  // all cs ds_reads done before overwrite
    if (t2 == 1) {
        #pragma unroll
        for (int t = 0; t < 4; ++t)
            #pragma unroll
            for (int r = 0; r < 4; ++r) {
                RD(0, stripe, (quad << 2) + r, (t << 4) + n) = accX[t][r];
                RD(1, stripe, (quad << 2) + r, (t << 4) + n) = accY[t][r];
            }
    }
    __syncthreads();
    if (t2 == 0) {
        // partials: plane off = col*4096 + row; accX[t] holds rows quad*4+0..3
        float* wsX = ws_part + (size_t)kc * OUTSZ;
        float* wsY = ws_part + (size_t)(8 + kc) * OUTSZ;
        const int rowbase = (rg << 7) + (stripe << 4) + (quad << 2);
        #pragma unroll
        for (int t = 0; t < 4; ++t) {
            float4 X, Y;
            #pragma unroll
            for (int r = 0; r < 4; ++r) {
                ((float*)&X)[r] = accX[t][r] + RD(0, stripe, (quad << 2) + r, (t << 4) + n);
                ((float*)&Y)[r] = accY[t][r] + RD(1, stripe, (quad << 2) + r, (t << 4) + n);
            }
            size_t off = (size_t)((t << 4) + n) * N_DIM + rowbase;
            *(float4*)(wsX + off) = X;
            *(float4*)(wsY + off) = Y;
        }
    }
}

// Sum the 8 K-chunk partials + fused epilogue. All arrays share off=b*4096+i.
__global__ __launch_bounds__(256) void pf_reduce(
        const float* __restrict__ ws_part,
        const float* __restrict__ c_f, const float* __restrict__ s_f,
        const float* __restrict__ P_in, const float* __restrict__ Q_in,
        float* __restrict__ out) {
    int e = (blockIdx.x * 256 + threadIdx.x) * 4;
    float4 X = *(const float4*)(ws_part + e);
    float4 Y = *(const float4*)(ws_part + 8 * OUTSZ + e);
    #pragma unroll
    for (int kc = 1; kc < 8; ++kc) {
        float4 x = *(const float4*)(ws_part + (size_t)kc * OUTSZ + e);
        float4 y = *(const float4*)(ws_part + (size_t)(8 + kc) * OUTSZ + e);
        X.x += x.x; X.y += x.y; X.z += x.z; X.w += x.w;
        Y.x += y.x; Y.y += y.y; Y.z += y.z; Y.w += y.w;
    }
    float4 c = *(const float4*)(c_f + e);
    float4 s = *(const float4*)(s_f + e);
    float4 P = *(const float4*)(P_in + e);
    float4 Q = *(const float4*)(Q_in + e);
    float4 rp, rq;
    rp.x = c.x * X.x + s.x * Y.x - P.x;  rq.x = s.x * X.x - c.x * Y.x - Q.x;
    rp.y = c.y * X.y + s.y * Y.y - P.y;  rq.y = s.y * X.y - c.y * Y.y - Q.y;
    rp.z = c.z * X.z + s.z * Y.z - P.z;  rq.z = s.z * X.z - c.z * Y.z - Q.z;
    rp.w = c.w * X.w + s.w * Y.w - P.w;  rq.w = s.w * X.w - c.w * Y.w - Q.w;
    *(float4*)(out + e) = rp;
    *(float4*)(out + OUTSZ + e) = rq;
}

extern "C" void kernel_launch(void* const* d_in, const int* in_sizes, int n_in,
                              void* d_out, int out_size, void* d_ws, size_t ws_size,
                              hipStream_t stream) {
    const float* Vmag = (const float*)d_in[0];
    const float* Vang = (const float*)d_in[1];
    const float* P_in = (const float*)d_in[2];
    const float* Q_in = (const float*)d_in[3];
    const float* G    = (const float*)d_in[4];
    const float* Bm   = (const float*)d_in[5];
    float* out = (float*)d_out;

    char* ws = (char*)d_ws;
    unsigned short* c_pk = (unsigned short*)(ws);                    // 512 KB
    unsigned short* s_pk = (unsigned short*)(ws + (512u << 10));     // 512 KB
    float* c_f = (float*)(ws + (1u << 20));                          // 1 MB
    float* s_f = (float*)(ws + (2u << 20));                          // 1 MB
    float* ws_part = (float*)(ws + (3u << 20));                      // 16 MB

    hipLaunchKernelGGL(pf_prep, dim3((B_DIM * N_DIM) / 256), dim3(256), 0, stream,
                       Vmag, Vang, c_pk, s_pk, c_f, s_f);
    hipLaunchKernelGGL(pf_gemm, dim3(256), dim3(1024), 0, stream,
                       G, Bm, c_pk, s_pk, ws_part);
    hipLaunchKernelGGL(pf_reduce, dim3(OUTSZ / 1024), dim3(256), 0, stream,
                       ws_part, c_f, s_f, P_in, Q_in, out);
}

// Round 8
// 169.304 us; speedup vs baseline: 1.0898x; 1.0315x over previous
//
#include <hip/hip_runtime.h>
#include <stdint.h>

#define N_DIM 4096
#define B_DIM 64
#define OUTSZ (B_DIM * N_DIM)

typedef __bf16 bf16x8 __attribute__((ext_vector_type(8)));
typedef float floatx4 __attribute__((ext_vector_type(4)));

union FragU { uint4 u; bf16x8 h; };

__device__ __forceinline__ unsigned short f2bf_rne(float f) {
    unsigned int u = __float_as_uint(f);
    u += 0x7fffu + ((u >> 16) & 1u);
    return (unsigned short)(u >> 16);
}

// c = Vmag*cos(ang), s = Vmag*sin(ang).
// fp32 copies in natural [b][j] layout (epilogue), bf16 copies packed in MFMA
// B-fragment order: idx = ((j>>3)*64 + b)*8 + (j&7)
__global__ __launch_bounds__(256) void pf_prep(
        const float* __restrict__ Vmag, const float* __restrict__ Vang,
        unsigned short* __restrict__ c_pk, unsigned short* __restrict__ s_pk,
        float* __restrict__ c_f, float* __restrict__ s_f) {
    int idx = blockIdx.x * 256 + threadIdx.x;   // = b*4096 + j
    int b = idx >> 12;
    int j = idx & 4095;
    float sv, cv;
    sincosf(Vang[idx], &sv, &cv);
    float v = Vmag[idx];
    float c = v * cv;
    float s = v * sv;
    c_f[idx] = c;
    s_f[idx] = s;
    int p = (((j >> 3) << 6) + b) * 8 + (j & 7);
    c_pk[p] = f2bf_rne(c);
    s_pk[p] = f2bf_rne(s);
}

// R1 structure (minimal fabric traffic, in-kernel epilogue) + deep pipeline.
// One block = 16 rows of G/B, 8 waves split K=4096 into 512-chunks, 16 iters
// of K=32 each. Issue order per iter: cs(i+1) first, then A(i+2) — in-order
// vmcnt retirement means using cs(i)/A(i) leaves A(i+1), cs(i+1), A(i+2)
// in flight (~16KB/wave outstanding). X = G*c + B*s ; Y = G*s - B*c.
__global__ __launch_bounds__(512, 2) void pf_gemm(
        const float* __restrict__ G, const float* __restrict__ Bm,
        const unsigned short* __restrict__ c_pk, const unsigned short* __restrict__ s_pk,
        const float* __restrict__ c_f, const float* __restrict__ s_f,
        const float* __restrict__ P_in, const float* __restrict__ Q_in,
        float* __restrict__ out) {
    __shared__ float red[2][8][16][66];
    const int tid = threadIdx.x;
    const int wave = tid >> 6;        // 0..7
    const int lane = tid & 63;
    const int n = lane & 15;
    const int quad = lane >> 4;
    const int i0 = blockIdx.x << 4;   // 16 rows per block
    const int kw = wave << 9;         // wave's K-chunk (512)

    const float* gp = G  + (size_t)(i0 + n) * N_DIM + kw + (quad << 3);
    const float* bp = Bm + (size_t)(i0 + n) * N_DIM + kw + (quad << 3);
    const unsigned short* cp = c_pk + ((size_t)(((kw >> 3) + quad) << 6) + n) * 8;
    const unsigned short* sp = s_pk + ((size_t)(((kw >> 3) + quad) << 6) + n) * 8;

    floatx4 accX[4], accY[4];
    #pragma unroll
    for (int t = 0; t < 4; ++t) {
        accX[t] = (floatx4){0.f, 0.f, 0.f, 0.f};
        accY[t] = (floatx4){0.f, 0.f, 0.f, 0.f};
    }

    // ---- pipelined operand state ----
    uint4 cu0[4], su0[4], cu1[4], su1[4];         // cs(i), cs(i+1)
    float4 g0a, g1a, h0a, h1a;                    // A(i)
    float4 g0b, g1b, h0b, h1b;                    // A(i+1)

    // prologue: cs(0), A(0), A(1)  [issue order defines vmcnt retirement order]
    #pragma unroll
    for (int t = 0; t < 4; ++t) cu0[t] = *(const uint4*)(cp + t * 128);
    #pragma unroll
    for (int t = 0; t < 4; ++t) su0[t] = *(const uint4*)(sp + t * 128);
    g0a = *(const float4*)gp;  g1a = *(const float4*)(gp + 4);
    h0a = *(const float4*)bp;  h1a = *(const float4*)(bp + 4);
    g0b = *(const float4*)(gp + 32);  g1b = *(const float4*)(gp + 36);
    h0b = *(const float4*)(bp + 32);  h1b = *(const float4*)(bp + 36);

    #pragma unroll 1
    for (int it = 0; it < 16; ++it) {
        // issue cs(i+1) then A(i+2): younger than the operands we wait on below
        if (it < 15) {
            const unsigned short* cn = cp + (it + 1) * 2048;
            const unsigned short* sn = sp + (it + 1) * 2048;
            #pragma unroll
            for (int t = 0; t < 4; ++t) cu1[t] = *(const uint4*)(cn + t * 128);
            #pragma unroll
            for (int t = 0; t < 4; ++t) su1[t] = *(const uint4*)(sn + t * 128);
        }
        float4 g0c, g1c, h0c, h1c;
        if (it < 14) {
            const float* gn = gp + (it + 2) * 32;
            const float* bn = bp + (it + 2) * 32;
            g0c = *(const float4*)gn;  g1c = *(const float4*)(gn + 4);
            h0c = *(const float4*)bn;  h1c = *(const float4*)(bn + 4);
        }

        bf16x8 ag, ah;
        ag[0] = (__bf16)g0a.x; ag[1] = (__bf16)g0a.y; ag[2] = (__bf16)g0a.z; ag[3] = (__bf16)g0a.w;
        ag[4] = (__bf16)g1a.x; ag[5] = (__bf16)g1a.y; ag[6] = (__bf16)g1a.z; ag[7] = (__bf16)g1a.w;
        ah[0] = (__bf16)h0a.x; ah[1] = (__bf16)h0a.y; ah[2] = (__bf16)h0a.z; ah[3] = (__bf16)h0a.w;
        ah[4] = (__bf16)h1a.x; ah[5] = (__bf16)h1a.y; ah[6] = (__bf16)h1a.z; ah[7] = (__bf16)h1a.w;

        // c-phase: X += G*c ; Y += B*(-c)
        #pragma unroll
        for (int t = 0; t < 4; ++t) {
            FragU cf, nf;
            cf.u = cu0[t];
            nf.u.x = cu0[t].x ^ 0x80008000u;
            nf.u.y = cu0[t].y ^ 0x80008000u;
            nf.u.z = cu0[t].z ^ 0x80008000u;
            nf.u.w = cu0[t].w ^ 0x80008000u;
            accX[t] = __builtin_amdgcn_mfma_f32_16x16x32_bf16(ag, cf.h, accX[t], 0, 0, 0);
            accY[t] = __builtin_amdgcn_mfma_f32_16x16x32_bf16(ah, nf.h, accY[t], 0, 0, 0);
        }
        // s-phase: X += B*s ; Y += G*s
        #pragma unroll
        for (int t = 0; t < 4; ++t) {
            FragU sf;
            sf.u = su0[t];
            accX[t] = __builtin_amdgcn_mfma_f32_16x16x32_bf16(ah, sf.h, accX[t], 0, 0, 0);
            accY[t] = __builtin_amdgcn_mfma_f32_16x16x32_bf16(ag, sf.h, accY[t], 0, 0, 0);
        }

        // rotate pipeline registers
        #pragma unroll
        for (int t = 0; t < 4; ++t) { cu0[t] = cu1[t]; su0[t] = su1[t]; }
        g0a = g0b; g1a = g1b; h0a = h0b; h1a = h1b;
        g0b = g0c; g1b = g1c; h0b = h0c; h1b = h1c;
    }

    // cross-wave reduction: C/D layout col(b)=lane&15, row(m)=quad*4+reg
    #pragma unroll
    for (int t = 0; t < 4; ++t)
        #pragma unroll
        for (int r = 0; r < 4; ++r) {
            if (wave >= 4) {
                red[0][wave - 4 + 4][(quad << 2) + r][(t << 4) + n] = accX[t][r];
                red[1][wave - 4 + 4][(quad << 2) + r][(t << 4) + n] = accY[t][r];
            }
        }
    // (waves 0-3 write after barrier-free? no — need full two-phase)
    if (wave >= 4) { /* wrote above */ } else {
        #pragma unroll
        for (int t = 0; t < 4; ++t)
            #pragma unroll
            for (int r = 0; r < 4; ++r) {
                red[0][wave][(quad << 2) + r][(t << 4) + n] = accX[t][r];
                red[1][wave][(quad << 2) + r][(t << 4) + n] = accY[t][r];
            }
    }
    __syncthreads();

    // 1024 outputs, 512 threads -> 2 each; fused epilogue
    for (int e = tid; e < 1024; e += 512) {
        int bb = e >> 4;
        int m = e & 15;
        float X = 0.f, Y = 0.f;
        #pragma unroll
        for (int w = 0; w < 8; ++w) {
            X += red[0][w][m][bb];
            Y += red[1][w][m][bb];
        }
        size_t off = (size_t)bb * N_DIM + i0 + m;
        float c = c_f[off], s = s_f[off];
        out[off] = c * X + s * Y - P_in[off];
        out[(size_t)OUTSZ + off] = s * X - c * Y - Q_in[off];
    }
}

extern "C" void kernel_launch(void* const* d_in, const int* in_sizes, int n_in,
                              void* d_out, int out_size, void* d_ws, size_t ws_size,
                              hipStream_t stream) {
    const float* Vmag = (const float*)d_in[0];
    const float* Vang = (const float*)d_in[1];
    const float* P_in = (const float*)d_in[2];
    const float* Q_in = (const float*)d_in[3];
    const float* G    = (const float*)d_in[4];
    const float* Bm   = (const float*)d_in[5];
    float* out = (float*)d_out;

    char* ws = (char*)d_ws;
    unsigned short* c_pk = (unsigned short*)(ws);                    // 512 KB
    unsigned short* s_pk = (unsigned short*)(ws + (512u << 10));     // 512 KB
    float* c_f = (float*)(ws + (1u << 20));                          // 1 MB
    float* s_f = (float*)(ws + (2u << 20));                          // 1 MB

    hipLaunchKernelGGL(pf_prep, dim3((B_DIM * N_DIM) / 256), dim3(256), 0, stream,
                       Vmag, Vang, c_pk, s_pk, c_f, s_f);
    hipLaunchKernelGGL(pf_gemm, dim3(N_DIM / 16), dim3(512), 0, stream,
                       G, Bm, c_pk, s_pk, c_f, s_f, P_in, Q_in, out);
}